// Round 9
// baseline (394.509 us; speedup 1.0000x reference)
//
#include <hip/hip_runtime.h>
#include <math.h>

#define N_NODES 50000
#define E_EDGES 800000
#define DIM 256      // IN_DIM = HID = 256 (= H*O for both layers)
#define HEADS 4
#define HO 64        // per-head output width (O1 = LAT = 64)
#define NEG_SLOPE 0.2f
#define SCAN_NBLK ((N_NODES + 255) / 256)   // 196
#define BT_ROWS 272  // 256 W^T cols + 8 logit cols (als,ald per head) + 8 zero pad

typedef __attribute__((ext_vector_type(8))) short bf16x8;
typedef __attribute__((ext_vector_type(4))) float f32x4;
typedef __attribute__((ext_vector_type(2))) float f32x2;

static __device__ inline ushort f2bf(float f) {
  union { float f; unsigned u; } v; v.f = f;
  unsigned r = (v.u + 0x7fff + ((v.u >> 16) & 1)) >> 16;  // RTNE
  return (ushort)r;
}
static __device__ inline float bf2f(ushort h) {
  union { unsigned u; float f; } v; v.u = ((unsigned)h) << 16;
  return v.f;
}

// ---- weight prep: W^T -> bf16 rows 0..255; rows 256..263 = W@a_src / W@a_dst
// per head (so logits fall out of the GEMM); rows 264..271 = zero pad. Both layers.
__global__ __launch_bounds__(256) void prep_weights(const float* __restrict__ W1,
                                                    const float* __restrict__ W2,
                                                    const float* __restrict__ as1,
                                                    const float* __restrict__ ad1,
                                                    const float* __restrict__ as2,
                                                    const float* __restrict__ ad2,
                                                    ushort* __restrict__ bt1,
                                                    ushort* __restrict__ bt2) {
  int b = blockIdx.x;
  int tid = threadIdx.x;
  if (b < 512) {             // transpose W -> bt rows 0..255
    const float* W = (b < 256) ? W1 : W2;
    ushort* bt = (b < 256) ? bt1 : bt2;
    int idx = ((b & 255) << 8) | tid;   // 0..65535
    int k = idx >> 8, n = idx & 255;
    bt[n * 256 + k] = f2bf(W[idx]);     // W[k][n] -> BT[n][k]
  } else {                   // b == 512: w_al rows for both layers
    int k = tid;
    for (int l = 0; l < 2; ++l) {
      const float* W = l ? W2 : W1;
      const float* as = l ? as2 : as1;
      const float* ad = l ? ad2 : ad1;
      ushort* bt = l ? bt2 : bt1;
      for (int h = 0; h < HEADS; ++h) {
        float s = 0.f, d = 0.f;
        for (int o = 0; o < HO; ++o) {
          float w = W[k * DIM + h * HO + o];
          s += w * as[h * HO + o];
          d += w * ad[h * HO + o];
        }
        bt[(256 + h) * 256 + k] = f2bf(s);
        bt[(260 + h) * 256 + k] = f2bf(d);
      }
      for (int j = 0; j < 8; ++j) bt[(264 + j) * 256 + k] = 0;
    }
  }
}

// ---------------- bf16 MFMA GEMM + fused logit columns ----------------
// Cbf16(Mx256) = A @ BT^T. by==0 blocks additionally compute the 16-wide
// "E" tile (BT rows 256..271) on their wn==0 waves; C-cols 0..3 = als heads,
// 4..7 = ald heads -> direct stores (each (row,head) written by one wave).
#define GBM 128
#define GBK 32
#define LDK 40   // padded LDS k-stride (ushorts): 80B rows, 2-way banks max

template <bool AF32>
__global__ __launch_bounds__(256) void gemm_mfma(const void* __restrict__ Av,
                                                 const ushort* __restrict__ Bt,
                                                 ushort* __restrict__ Cbf,
                                                 float* __restrict__ als,
                                                 float* __restrict__ ald, int M) {
  __shared__ __align__(16) ushort As[GBM][LDK];
  __shared__ __align__(16) ushort Bs[GBM][LDK];
  __shared__ __align__(16) ushort Es[16][LDK];
  const int tid = threadIdx.x;
  const int lane = tid & 63;
  const int wave = tid >> 6;
  const int row0 = blockIdx.x * GBM;
  const int col0 = blockIdx.y * GBM;
  const int wm = (wave & 1) * 64;
  const int wn = (wave >> 1) * 64;
  const int rA = lane & 15;
  const int kb = (lane >> 4) * 8;
  const bool doE = (blockIdx.y == 0);

  f32x4 acc[4][4] = {};
  f32x4 accE[4] = {};

  for (int k0 = 0; k0 < DIM; k0 += GBK) {
    if constexpr (AF32) {
      const float* A = (const float*)Av;
#pragma unroll
      for (int qq = 0; qq < 4; ++qq) {
        int q = tid + qq * 256;
        int r = q >> 3, c = q & 7;
        int grow = row0 + r;
        float4 v = make_float4(0.f, 0.f, 0.f, 0.f);
        if (grow < M) v = *(const float4*)&A[(size_t)grow * DIM + k0 + c * 4];
        ushort4 h;
        h.x = f2bf(v.x); h.y = f2bf(v.y); h.z = f2bf(v.z); h.w = f2bf(v.w);
        *(ushort4*)&As[r][c * 4] = h;
      }
    } else {
      const ushort* A = (const ushort*)Av;
#pragma unroll
      for (int qq = 0; qq < 2; ++qq) {
        int q = tid + qq * 256;
        int r = q >> 2, c = q & 3;
        int grow = row0 + r;
        bf16x8 v = {};
        if (grow < M) v = *(const bf16x8*)&A[(size_t)grow * DIM + k0 + c * 8];
        *(bf16x8*)&As[r][c * 8] = v;
      }
    }
    // B tile: 128 rows x 32 bf16
#pragma unroll
    for (int qq = 0; qq < 2; ++qq) {
      int q = tid + qq * 256;
      int r = q >> 2, c = q & 3;
      *(bf16x8*)&Bs[r][c * 8] = *(const bf16x8*)&Bt[(size_t)(col0 + r) * DIM + k0 + c * 8];
    }
    // E tile: BT rows 256..271 (by==0 blocks only)
    if (doE && tid < 64) {
      int r = tid >> 2, c = tid & 3;
      *(bf16x8*)&Es[r][c * 8] = *(const bf16x8*)&Bt[(size_t)(256 + r) * DIM + k0 + c * 8];
    }
    __syncthreads();

    bf16x8 af[4], bfr[4];
#pragma unroll
    for (int mi = 0; mi < 4; ++mi) af[mi] = *(const bf16x8*)&As[wm + mi * 16 + rA][kb];
#pragma unroll
    for (int ni = 0; ni < 4; ++ni) bfr[ni] = *(const bf16x8*)&Bs[wn + ni * 16 + rA][kb];
    if (doE && wn == 0) {
      bf16x8 ef = *(const bf16x8*)&Es[rA][kb];
#pragma unroll
      for (int mi = 0; mi < 4; ++mi)
        accE[mi] = __builtin_amdgcn_mfma_f32_16x16x32_bf16(af[mi], ef, accE[mi], 0, 0, 0);
    }
#pragma unroll
    for (int mi = 0; mi < 4; ++mi)
#pragma unroll
      for (int ni = 0; ni < 4; ++ni)
        acc[mi][ni] = __builtin_amdgcn_mfma_f32_16x16x32_bf16(af[mi], bfr[ni], acc[mi][ni], 0, 0, 0);
    __syncthreads();
  }

  // C/D layout: col = lane&15, row = (lane>>4)*4 + reg. Emit bf16.
#pragma unroll
  for (int mi = 0; mi < 4; ++mi) {
    int rbase = row0 + wm + mi * 16 + (lane >> 4) * 4;
#pragma unroll
    for (int ni = 0; ni < 4; ++ni) {
      int col = col0 + wn + ni * 16 + (lane & 15);
#pragma unroll
      for (int r = 0; r < 4; ++r) {
        int row = rbase + r;
        if (row < M) Cbf[(size_t)row * DIM + col] = f2bf(acc[mi][ni][r]);
      }
    }
  }

  // logit stores: E-tile cols 0..3 = als[head], 4..7 = ald[head]
  if (doE && wn == 0) {
    int col16 = lane & 15;
#pragma unroll
    for (int mi = 0; mi < 4; ++mi) {
      int rbase = row0 + wm + mi * 16 + (lane >> 4) * 4;
#pragma unroll
      for (int r = 0; r < 4; ++r) {
        int row = rbase + r;
        if (row < M && col16 < 8) {
          float v = accE[mi][r];
          if (col16 < 4) als[row * HEADS + col16] = v;
          else           ald[row * HEADS + (col16 - 4)] = v;
        }
      }
    }
  }
}

// ---------------- CSR build ----------------
__global__ __launch_bounds__(256) void histo(const int* __restrict__ dst, int* __restrict__ deg) {
  int e = blockIdx.x * blockDim.x + threadIdx.x;
  if (e < E_EDGES) atomicAdd(&deg[dst[e]], 1);
}

__global__ __launch_bounds__(256) void scan1(const int* __restrict__ deg,
                                             int* __restrict__ excl,
                                             int* __restrict__ blockSums) {
  __shared__ int tmp[256];
  int i = blockIdx.x * 256 + threadIdx.x;
  int v = (i < N_NODES) ? deg[i] : 0;
  tmp[threadIdx.x] = v;
  __syncthreads();
  for (int off = 1; off < 256; off <<= 1) {
    int t = (threadIdx.x >= off) ? tmp[threadIdx.x - off] : 0;
    __syncthreads();
    tmp[threadIdx.x] += t;
    __syncthreads();
  }
  int incl = tmp[threadIdx.x];
  if (i < N_NODES) excl[i] = incl - v;
  if (threadIdx.x == 255) blockSums[blockIdx.x] = incl;
}

__global__ __launch_bounds__(256) void scan2(int* __restrict__ blockSums) {
  __shared__ int tmp[256];
  int i = threadIdx.x;
  int v = (i < SCAN_NBLK) ? blockSums[i] : 0;
  tmp[i] = v;
  __syncthreads();
  for (int off = 1; off < 256; off <<= 1) {
    int t = (i >= off) ? tmp[i - off] : 0;
    __syncthreads();
    tmp[i] += t;
    __syncthreads();
  }
  if (i < SCAN_NBLK) blockSums[i] = tmp[i] - v;  // exclusive
}

__global__ __launch_bounds__(256) void scan3(int* __restrict__ excl,
                                             const int* __restrict__ blockSums,
                                             int* __restrict__ cursor) {
  int i = blockIdx.x * 256 + threadIdx.x;
  if (i < N_NODES) {
    int r = excl[i] + blockSums[blockIdx.x];
    excl[i] = r;
    cursor[i] = r;
  }
}

__global__ __launch_bounds__(256) void scatter(const int* __restrict__ src,
                                               const int* __restrict__ dst,
                                               int* __restrict__ cursor,
                                               int* __restrict__ csr_src) {
  int e = blockIdx.x * blockDim.x + threadIdx.x;
  if (e >= E_EDGES) return;
  int pos = atomicAdd(&cursor[dst[e]], 1);
  csr_src[pos] = src[e];
}

// ---------------- aggregation core: half-wave per edge, bf16 h rows (R4 layout) ----------------
// lane: li = lane&31, half = lane>>5; lane covers 8 cols c0 = li*8; head = li>>3.
// virtual edge index it == deg is the self-loop. Packed f32x2 accumulate (v_pk_fma_f32).
#define AGG_BODY(S)                                                         \
  {                                                                         \
    float e0 = als[(S) * HEADS + head] + aldv;                              \
    e0 = e0 > 0.f ? e0 : NEG_SLOPE * e0;                                    \
    float p = __expf(e0);                                                   \
    bf16x8 hv = *(const bf16x8*)&hbf[(size_t)(S) * DIM + c0];               \
    den += p;                                                               \
    const uint* uu = (const uint*)&hv;                                      \
    f32x2 pp = {p, p};                                                      \
    _Pragma("unroll")                                                       \
    for (int q = 0; q < 4; ++q) {                                           \
      f32x2 hh;                                                             \
      hh.x = __uint_as_float(uu[q] << 16);                                  \
      hh.y = __uint_as_float(uu[q] & 0xffff0000u);                          \
      acc2[q] += pp * hh;                                                   \
    }                                                                       \
  }

// shared gather loop: 3 edges in flight per half-wave
#define AGG_LOOP                                                            \
  int rs = rowptr[node];                                                    \
  int deg = ((node < N_NODES - 1) ? rowptr[node + 1] : E_EDGES) - rs;       \
  float aldv = ald[node * HEADS + head];                                    \
  float den = 0.f;                                                          \
  f32x2 acc2[4] = {};                                                       \
  int total = deg + 1;                                                      \
  int it = half;                                                            \
  for (; it + 4 < total; it += 6) {                                         \
    int s0 = csr_src[rs + it];                                              \
    int s1 = csr_src[rs + it + 2];                                          \
    int s2 = (it + 4 < deg) ? csr_src[rs + it + 4] : node;                  \
    AGG_BODY(s0)                                                            \
    AGG_BODY(s1)                                                            \
    AGG_BODY(s2)                                                            \
  }                                                                         \
  for (; it < total; it += 2) {                                             \
    int s0 = (it < deg) ? csr_src[rs + it] : node;                          \
    AGG_BODY(s0)                                                            \
  }                                                                         \
  den += __shfl_xor(den, 32, 64);                                           \
  float accs[8];                                                            \
  _Pragma("unroll")                                                         \
  for (int q = 0; q < 4; ++q) {                                             \
    accs[2 * q] = acc2[q].x + __shfl_xor(acc2[q].x, 32, 64);                \
    accs[2 * q + 1] = acc2[q].y + __shfl_xor(acc2[q].y, 32, 64);            \
  }

// layer-1: finalize = +bias, ELU -> bf16 x2 (layer-2 GEMM A-operand)
__global__ __launch_bounds__(256) void agg1(const int* __restrict__ rowptr,
                                            const int* __restrict__ csr_src,
                                            const ushort* __restrict__ hbf,
                                            const float* __restrict__ als,
                                            const float* __restrict__ ald,
                                            const float* __restrict__ bias,
                                            ushort* __restrict__ x2) {
  int gid = blockIdx.x * blockDim.x + threadIdx.x;
  int node = gid >> 6;
  if (node >= N_NODES) return;
  int lane = threadIdx.x & 63;
  int li = lane & 31, half = lane >> 5;
  int head = li >> 3;
  int c0 = li * 8;
  AGG_LOOP
  if (half == 0) {
    float inv = 1.f / den;
    ushort4 o0, o1;
    float r[8];
#pragma unroll
    for (int j = 0; j < 8; ++j) {
      r[j] = accs[j] * inv + bias[c0 + j];
      r[j] = r[j] > 0.f ? r[j] : expm1f(r[j]);   // ELU
    }
    o0.x = f2bf(r[0]); o0.y = f2bf(r[1]); o0.z = f2bf(r[2]); o0.w = f2bf(r[3]);
    o1.x = f2bf(r[4]); o1.y = f2bf(r[5]); o1.z = f2bf(r[6]); o1.w = f2bf(r[7]);
    *(ushort4*)&x2[(size_t)node * DIM + c0] = o0;
    *(ushort4*)&x2[(size_t)node * DIM + c0 + 4] = o1;
  }
}

// layer-2: finalize = mean over heads, +b2 -> fp32 z (N x 64)
__global__ __launch_bounds__(256) void agg2(const int* __restrict__ rowptr,
                                            const int* __restrict__ csr_src,
                                            const ushort* __restrict__ hbf,
                                            const float* __restrict__ als,
                                            const float* __restrict__ ald,
                                            const float* __restrict__ b2,
                                            float* __restrict__ z) {
  int gid = blockIdx.x * blockDim.x + threadIdx.x;
  int node = gid >> 6;
  if (node >= N_NODES) return;
  int lane = threadIdx.x & 63;
  int li = lane & 31, half = lane >> 5;
  int head = li >> 3;
  int c0 = li * 8;
  AGG_LOOP
  float inv = 1.f / den;
  float r[8];
#pragma unroll
  for (int j = 0; j < 8; ++j) {
    r[j] = accs[j] * inv;
    r[j] += __shfl_xor(r[j], 8, 64);    // head 0<->1 (and 2<->3)
    r[j] += __shfl_xor(r[j], 16, 64);   // heads (0,1)<->(2,3)
  }
  if (lane < 8) {   // half==0, li<8: cols li*8..li*8+7 of the 64-wide z row
    int zc = li * 8;
    float4 v0 = make_float4(r[0] * 0.25f + b2[zc + 0], r[1] * 0.25f + b2[zc + 1],
                            r[2] * 0.25f + b2[zc + 2], r[3] * 0.25f + b2[zc + 3]);
    float4 v1 = make_float4(r[4] * 0.25f + b2[zc + 4], r[5] * 0.25f + b2[zc + 5],
                            r[6] * 0.25f + b2[zc + 6], r[7] * 0.25f + b2[zc + 7]);
    *(float4*)&z[(size_t)node * HO + zc] = v0;
    *(float4*)&z[(size_t)node * HO + zc + 4] = v1;
  }
}

// ---------------- decoder ----------------
__global__ __launch_bounds__(256) void decoder(const int* __restrict__ src,
                                               const int* __restrict__ dst,
                                               const float* __restrict__ z,
                                               float* __restrict__ out) {
  long long gid = (long long)blockIdx.x * blockDim.x + threadIdx.x;
  int e = (int)(gid >> 4);
  if (e >= E_EDGES) return;
  int l = threadIdx.x & 15;
  int s = src[e];
  int d = dst[e];
  float4 a = *(const float4*)&z[(size_t)s * HO + l * 4];
  float4 b = *(const float4*)&z[(size_t)d * HO + l * 4];
  float v = a.x * b.x + a.y * b.y + a.z * b.z + a.w * b.w;
#pragma unroll
  for (int off = 8; off >= 1; off >>= 1) v += __shfl_xor(v, off, 64);
  if (l == 0) out[e] = v;
}

extern "C" void kernel_launch(void* const* d_in, const int* in_sizes, int n_in,
                              void* d_out, int out_size, void* d_ws, size_t ws_size,
                              hipStream_t stream) {
  const float* x      = (const float*)d_in[0];
  const int*   ei     = (const int*)d_in[1];
  const float* W1     = (const float*)d_in[2];
  const float* a_src1 = (const float*)d_in[3];
  const float* a_dst1 = (const float*)d_in[4];
  const float* b1     = (const float*)d_in[5];
  const float* W2     = (const float*)d_in[6];
  const float* a_src2 = (const float*)d_in[7];
  const float* a_dst2 = (const float*)d_in[8];
  const float* b2     = (const float*)d_in[9];
  const int* src = ei;
  const int* dst = ei + E_EDGES;
  float* logits = (float*)d_out;

  float* zlat = (float*)d_ws;                          // N*64 fp32
  float* als1 = zlat + (size_t)N_NODES * HO;
  float* ald1 = als1 + N_NODES * HEADS;
  float* als2 = ald1 + N_NODES * HEADS;
  float* ald2 = als2 + N_NODES * HEADS;
  int* deg      = (int*)(ald2 + N_NODES * HEADS);
  int* rowptr   = deg + N_NODES;
  int* cursor   = rowptr + N_NODES;
  int* blockSums= cursor + N_NODES;
  int* csr_src  = blockSums + 256;
  ushort* hbf   = (ushort*)(csr_src + E_EDGES);        // N*256 bf16 (h1, then h2)
  ushort* x2bf  = hbf + (size_t)N_NODES * DIM;         // N*256 bf16 (elu(gat1))
  ushort* bt1   = x2bf + (size_t)N_NODES * DIM;        // 2 x 272*256 (W^T + logit cols)
  ushort* bt2   = bt1 + BT_ROWS * DIM;

  dim3 blk(256);
  dim3 gemmGrid((N_NODES + GBM - 1) / GBM, DIM / GBM); // 391 x 2
  int nodeBlocks = (N_NODES * 64 + 255) / 256;
  int edgeThreadBlocks = (E_EDGES + 255) / 256;
  int decBlocks  = (int)(((long long)E_EDGES * 16 + 255) / 256);

  // ---- CSR build (graph shared by both layers) ----
  hipMemsetAsync(deg, 0, N_NODES * sizeof(int), stream);
  hipLaunchKernelGGL(histo, dim3(edgeThreadBlocks), blk, 0, stream, dst, deg);
  hipLaunchKernelGGL(scan1, dim3(SCAN_NBLK), blk, 0, stream, deg, rowptr, blockSums);
  hipLaunchKernelGGL(scan2, dim3(1), blk, 0, stream, blockSums);
  hipLaunchKernelGGL(scan3, dim3(SCAN_NBLK), blk, 0, stream, rowptr, blockSums, cursor);
  hipLaunchKernelGGL(scatter, dim3(edgeThreadBlocks), blk, 0, stream, src, dst, cursor, csr_src);

  // ---- weight prep (transposes + fused logit columns, both layers) ----
  hipLaunchKernelGGL(prep_weights, dim3(513), blk, 0, stream,
                     W1, W2, a_src1, a_dst1, a_src2, a_dst2, bt1, bt2);

  // ---- layer 1 (A = fp32 x; GEMM also emits als1/ald1) ----
  gemm_mfma<true><<<gemmGrid, blk, 0, stream>>>((const void*)x, bt1, hbf, als1, ald1, N_NODES);
  hipLaunchKernelGGL(agg1, dim3(nodeBlocks), blk, 0, stream, rowptr, csr_src, hbf, als1, ald1, b1, x2bf);

  // ---- layer 2 (A = bf16 x2; GEMM also emits als2/ald2) ----
  gemm_mfma<false><<<gemmGrid, blk, 0, stream>>>((const void*)x2bf, bt2, hbf, als2, ald2, N_NODES);
  hipLaunchKernelGGL(agg2, dim3(nodeBlocks), blk, 0, stream, rowptr, csr_src, hbf, als2, ald2, b2, zlat);

  // ---- decoder ----
  hipLaunchKernelGGL(decoder, dim3(decBlocks), blk, 0, stream, src, dst, zlat, logits);
}

// Round 10
// 382.340 us; speedup vs baseline: 1.0318x; 1.0318x over previous
//
#include <hip/hip_runtime.h>
#include <math.h>

#define N_NODES 50000
#define E_EDGES 800000
#define DIM 256      // IN_DIM = HID = 256 (= H*O for both layers)
#define HEADS 4
#define HO 64        // per-head output width (O1 = LAT = 64)
#define NEG_SLOPE 0.2f
#define SCAN_NBLK ((N_NODES + 255) / 256)   // 196

typedef __attribute__((ext_vector_type(8))) short bf16x8;
typedef __attribute__((ext_vector_type(4))) float f32x4;
typedef __attribute__((ext_vector_type(2))) float f32x2;

static __device__ inline ushort f2bf(float f) {
  union { float f; unsigned u; } v; v.f = f;
  unsigned r = (v.u + 0x7fff + ((v.u >> 16) & 1)) >> 16;  // RTNE
  return (ushort)r;
}
static __device__ inline float bf2f(ushort h) {
  union { unsigned u; float f; } v; v.u = ((unsigned)h) << 16;
  return v.f;
}

// Both W (256x256) fp32 -> W^T as bf16 (single plane), one launch
__global__ __launch_bounds__(256) void cvt_T2(const float* __restrict__ W1,
                                              const float* __restrict__ W2,
                                              ushort* __restrict__ bt1,
                                              ushort* __restrict__ bt2) {
  int gidx = blockIdx.x * 256 + threadIdx.x;   // 131072 threads
  const float* W = (gidx < DIM * DIM) ? W1 : W2;
  ushort* bt = (gidx < DIM * DIM) ? bt1 : bt2;
  int idx = gidx & (DIM * DIM - 1);
  int k = idx >> 8, n = idx & 255;
  bt[n * 256 + k] = f2bf(W[idx]);              // W[k][n] -> BT[n][k]
}

// ---------------- bf16 MFMA GEMM: Cbf16(Mx256) = A @ BT^T ----------------
// A fp32 (converted during staging) or bf16 (direct). BT pre-transposed bf16.
// 128x128 tile, 4 waves, 16x16x32 MFMA, single pass. (R8-proven form.)
#define GBM 128
#define GBK 32
#define LDK 40   // padded LDS k-stride (ushorts): 80B rows, 2-way banks max

template <bool AF32>
__global__ __launch_bounds__(256) void gemm_mfma(const void* __restrict__ Av,
                                                 const ushort* __restrict__ Bt,
                                                 ushort* __restrict__ Cbf, int M) {
  __shared__ __align__(16) ushort As[GBM][LDK];
  __shared__ __align__(16) ushort Bs[GBM][LDK];
  const int tid = threadIdx.x;
  const int lane = tid & 63;
  const int wave = tid >> 6;
  const int row0 = blockIdx.x * GBM;
  const int col0 = blockIdx.y * GBM;
  const int wm = (wave & 1) * 64;
  const int wn = (wave >> 1) * 64;
  const int rA = lane & 15;
  const int kb = (lane >> 4) * 8;

  f32x4 acc[4][4] = {};

  for (int k0 = 0; k0 < DIM; k0 += GBK) {
    if constexpr (AF32) {
      const float* A = (const float*)Av;
      // A tile: 128 rows x 32 fp32 -> bf16. 1024 float4 chunks, 4 per thread.
#pragma unroll
      for (int qq = 0; qq < 4; ++qq) {
        int q = tid + qq * 256;
        int r = q >> 3, c = q & 7;
        int grow = row0 + r;
        float4 v = make_float4(0.f, 0.f, 0.f, 0.f);
        if (grow < M) v = *(const float4*)&A[(size_t)grow * DIM + k0 + c * 4];
        ushort4 h;
        h.x = f2bf(v.x); h.y = f2bf(v.y); h.z = f2bf(v.z); h.w = f2bf(v.w);
        *(ushort4*)&As[r][c * 4] = h;
      }
    } else {
      const ushort* A = (const ushort*)Av;
      // A tile: 128 rows x 32 bf16. 512 chunks of 8, 2 per thread.
#pragma unroll
      for (int qq = 0; qq < 2; ++qq) {
        int q = tid + qq * 256;
        int r = q >> 2, c = q & 3;
        int grow = row0 + r;
        bf16x8 v = {};
        if (grow < M) v = *(const bf16x8*)&A[(size_t)grow * DIM + k0 + c * 8];
        *(bf16x8*)&As[r][c * 8] = v;
      }
    }
    // B tile: 128 rows x 32 bf16. 512 chunks of 8, 2 per thread.
#pragma unroll
    for (int qq = 0; qq < 2; ++qq) {
      int q = tid + qq * 256;
      int r = q >> 2, c = q & 3;
      *(bf16x8*)&Bs[r][c * 8] = *(const bf16x8*)&Bt[(size_t)(col0 + r) * DIM + k0 + c * 8];
    }
    __syncthreads();

    bf16x8 af[4], bfr[4];
#pragma unroll
    for (int mi = 0; mi < 4; ++mi) af[mi] = *(const bf16x8*)&As[wm + mi * 16 + rA][kb];
#pragma unroll
    for (int ni = 0; ni < 4; ++ni) bfr[ni] = *(const bf16x8*)&Bs[wn + ni * 16 + rA][kb];
#pragma unroll
    for (int mi = 0; mi < 4; ++mi)
#pragma unroll
      for (int ni = 0; ni < 4; ++ni)
        acc[mi][ni] = __builtin_amdgcn_mfma_f32_16x16x32_bf16(af[mi], bfr[ni], acc[mi][ni], 0, 0, 0);
    __syncthreads();
  }

  // C/D layout: col = lane&15, row = (lane>>4)*4 + reg. Emit bf16.
#pragma unroll
  for (int mi = 0; mi < 4; ++mi) {
    int rbase = row0 + wm + mi * 16 + (lane >> 4) * 4;
#pragma unroll
    for (int ni = 0; ni < 4; ++ni) {
      int col = col0 + wn + ni * 16 + (lane & 15);
#pragma unroll
      for (int r = 0; r < 4; ++r) {
        int row = rbase + r;
        if (row < M) Cbf[(size_t)row * DIM + col] = f2bf(acc[mi][ni][r]);
      }
    }
  }
}

// ---------------- per-node attention logits (bf16 h) ----------------
__global__ __launch_bounds__(256) void attn_logits(const ushort* __restrict__ h,
                                                   const float* __restrict__ a_src,
                                                   const float* __restrict__ a_dst,
                                                   float* __restrict__ al_s,
                                                   float* __restrict__ al_d) {
  int gid = blockIdx.x * blockDim.x + threadIdx.x;
  int node = gid >> 6;
  int lane = threadIdx.x & 63;
  if (node >= N_NODES) return;
  ushort4 hv = *(const ushort4*)&h[(size_t)node * DIM + lane * 4];
  float4 as = *(const float4*)&a_src[lane * 4];
  float4 ad = *(const float4*)&a_dst[lane * 4];
  float h0 = bf2f(hv.x), h1 = bf2f(hv.y), h2 = bf2f(hv.z), h3 = bf2f(hv.w);
  float s = h0 * as.x + h1 * as.y + h2 * as.z + h3 * as.w;
  float d = h0 * ad.x + h1 * ad.y + h2 * ad.z + h3 * ad.w;
#pragma unroll
  for (int off = 8; off >= 1; off >>= 1) {
    s += __shfl_xor(s, off, 64);
    d += __shfl_xor(d, off, 64);
  }
  if ((lane & 15) == 0) {
    int head = lane >> 4;
    al_s[node * HEADS + head] = s;
    al_d[node * HEADS + head] = d;
  }
}

// ---------------- CSR build ----------------
__global__ __launch_bounds__(256) void histo(const int* __restrict__ dst, int* __restrict__ deg) {
  int e = blockIdx.x * blockDim.x + threadIdx.x;
  if (e < E_EDGES) atomicAdd(&deg[dst[e]], 1);
}

__global__ __launch_bounds__(256) void scan1(const int* __restrict__ deg,
                                             int* __restrict__ excl,
                                             int* __restrict__ blockSums) {
  __shared__ int tmp[256];
  int i = blockIdx.x * 256 + threadIdx.x;
  int v = (i < N_NODES) ? deg[i] : 0;
  tmp[threadIdx.x] = v;
  __syncthreads();
  for (int off = 1; off < 256; off <<= 1) {
    int t = (threadIdx.x >= off) ? tmp[threadIdx.x - off] : 0;
    __syncthreads();
    tmp[threadIdx.x] += t;
    __syncthreads();
  }
  int incl = tmp[threadIdx.x];
  if (i < N_NODES) excl[i] = incl - v;
  if (threadIdx.x == 255) blockSums[blockIdx.x] = incl;
}

__global__ __launch_bounds__(256) void scan2(int* __restrict__ blockSums) {
  __shared__ int tmp[256];
  int i = threadIdx.x;
  int v = (i < SCAN_NBLK) ? blockSums[i] : 0;
  tmp[i] = v;
  __syncthreads();
  for (int off = 1; off < 256; off <<= 1) {
    int t = (i >= off) ? tmp[i - off] : 0;
    __syncthreads();
    tmp[i] += t;
    __syncthreads();
  }
  if (i < SCAN_NBLK) blockSums[i] = tmp[i] - v;  // exclusive
}

__global__ __launch_bounds__(256) void scan3(int* __restrict__ excl,
                                             const int* __restrict__ blockSums,
                                             int* __restrict__ cursor) {
  int i = blockIdx.x * 256 + threadIdx.x;
  if (i < N_NODES) {
    int r = excl[i] + blockSums[blockIdx.x];
    excl[i] = r;
    cursor[i] = r;
  }
}

// scatter: CSR src ids AND original edge ids (for CSR-ordered decoder)
__global__ __launch_bounds__(256) void scatter(const int* __restrict__ src,
                                               const int* __restrict__ dst,
                                               int* __restrict__ cursor,
                                               int* __restrict__ csr_src,
                                               int* __restrict__ csr_eid) {
  int e = blockIdx.x * blockDim.x + threadIdx.x;
  if (e >= E_EDGES) return;
  int pos = atomicAdd(&cursor[dst[e]], 1);
  csr_src[pos] = src[e];
  csr_eid[pos] = e;
}

// ---------------- aggregation core: half-wave per edge, bf16 h rows (R4 layout) ----------------
// lane: li = lane&31, half = lane>>5; lane covers 8 cols c0 = li*8; head = li>>3.
// virtual edge index it == deg is the self-loop. Packed f32x2 accumulate (v_pk_fma_f32).
#define AGG_BODY(S)                                                         \
  {                                                                         \
    float e0 = als[(S) * HEADS + head] + aldv;                              \
    e0 = e0 > 0.f ? e0 : NEG_SLOPE * e0;                                    \
    float p = __expf(e0);                                                   \
    bf16x8 hv = *(const bf16x8*)&hbf[(size_t)(S) * DIM + c0];               \
    den += p;                                                               \
    const uint* uu = (const uint*)&hv;                                      \
    f32x2 pp = {p, p};                                                      \
    _Pragma("unroll")                                                       \
    for (int q = 0; q < 4; ++q) {                                           \
      f32x2 hh;                                                             \
      hh.x = __uint_as_float(uu[q] << 16);                                  \
      hh.y = __uint_as_float(uu[q] & 0xffff0000u);                          \
      acc2[q] += pp * hh;                                                   \
    }                                                                       \
  }

// shared gather loop: 3 edges in flight per half-wave
#define AGG_LOOP                                                            \
  int rs = rowptr[node];                                                    \
  int deg = ((node < N_NODES - 1) ? rowptr[node + 1] : E_EDGES) - rs;       \
  float aldv = ald[node * HEADS + head];                                    \
  float den = 0.f;                                                          \
  f32x2 acc2[4] = {};                                                       \
  int total = deg + 1;                                                      \
  int it = half;                                                            \
  for (; it + 4 < total; it += 6) {                                         \
    int s0 = csr_src[rs + it];                                              \
    int s1 = csr_src[rs + it + 2];                                          \
    int s2 = (it + 4 < deg) ? csr_src[rs + it + 4] : node;                  \
    AGG_BODY(s0)                                                            \
    AGG_BODY(s1)                                                            \
    AGG_BODY(s2)                                                            \
  }                                                                         \
  for (; it < total; it += 2) {                                             \
    int s0 = (it < deg) ? csr_src[rs + it] : node;                          \
    AGG_BODY(s0)                                                            \
  }                                                                         \
  den += __shfl_xor(den, 32, 64);                                           \
  float accs[8];                                                            \
  _Pragma("unroll")                                                         \
  for (int q = 0; q < 4; ++q) {                                             \
    accs[2 * q] = acc2[q].x + __shfl_xor(acc2[q].x, 32, 64);                \
    accs[2 * q + 1] = acc2[q].y + __shfl_xor(acc2[q].y, 32, 64);            \
  }

// layer-1: finalize = +bias, ELU -> bf16 x2 (layer-2 GEMM A-operand)
__global__ __launch_bounds__(256) void agg1(const int* __restrict__ rowptr,
                                            const int* __restrict__ csr_src,
                                            const ushort* __restrict__ hbf,
                                            const float* __restrict__ als,
                                            const float* __restrict__ ald,
                                            const float* __restrict__ bias,
                                            ushort* __restrict__ x2) {
  int gid = blockIdx.x * blockDim.x + threadIdx.x;
  int node = gid >> 6;
  if (node >= N_NODES) return;
  int lane = threadIdx.x & 63;
  int li = lane & 31, half = lane >> 5;
  int head = li >> 3;
  int c0 = li * 8;
  AGG_LOOP
  if (half == 0) {
    float inv = 1.f / den;
    ushort4 o0, o1;
    float r[8];
#pragma unroll
    for (int j = 0; j < 8; ++j) {
      r[j] = accs[j] * inv + bias[c0 + j];
      r[j] = r[j] > 0.f ? r[j] : expm1f(r[j]);   // ELU
    }
    o0.x = f2bf(r[0]); o0.y = f2bf(r[1]); o0.z = f2bf(r[2]); o0.w = f2bf(r[3]);
    o1.x = f2bf(r[4]); o1.y = f2bf(r[5]); o1.z = f2bf(r[6]); o1.w = f2bf(r[7]);
    *(ushort4*)&x2[(size_t)node * DIM + c0] = o0;
    *(ushort4*)&x2[(size_t)node * DIM + c0 + 4] = o1;
  }
}

// layer-2: finalize = mean over heads, +b2 -> fp32 z (N x 64)
__global__ __launch_bounds__(256) void agg2(const int* __restrict__ rowptr,
                                            const int* __restrict__ csr_src,
                                            const ushort* __restrict__ hbf,
                                            const float* __restrict__ als,
                                            const float* __restrict__ ald,
                                            const float* __restrict__ b2,
                                            float* __restrict__ z) {
  int gid = blockIdx.x * blockDim.x + threadIdx.x;
  int node = gid >> 6;
  if (node >= N_NODES) return;
  int lane = threadIdx.x & 63;
  int li = lane & 31, half = lane >> 5;
  int head = li >> 3;
  int c0 = li * 8;
  AGG_LOOP
  float inv = 1.f / den;
  float r[8];
#pragma unroll
  for (int j = 0; j < 8; ++j) {
    r[j] = accs[j] * inv;
    r[j] += __shfl_xor(r[j], 8, 64);    // head 0<->1 (and 2<->3)
    r[j] += __shfl_xor(r[j], 16, 64);   // heads (0,1)<->(2,3)
  }
  if (lane < 8) {   // half==0, li<8: cols li*8..li*8+7 of the 64-wide z row
    int zc = li * 8;
    float4 v0 = make_float4(r[0] * 0.25f + b2[zc + 0], r[1] * 0.25f + b2[zc + 1],
                            r[2] * 0.25f + b2[zc + 2], r[3] * 0.25f + b2[zc + 3]);
    float4 v1 = make_float4(r[4] * 0.25f + b2[zc + 4], r[5] * 0.25f + b2[zc + 5],
                            r[6] * 0.25f + b2[zc + 6], r[7] * 0.25f + b2[zc + 7]);
    *(float4*)&z[(size_t)node * HO + zc] = v0;
    *(float4*)&z[(size_t)node * HO + zc + 4] = v1;
  }
}

// ---------------- decoder, CSR (dst-major) order ----------------
// wave per dst node; z[dst] loaded once into registers, reused across its edges.
// 4 groups of 16 lanes; group g handles edge slots {g, g+4, ...}; out[eid] scatter.
__global__ __launch_bounds__(256) void decoder_csr(const int* __restrict__ rowptr,
                                                   const int* __restrict__ csr_src,
                                                   const int* __restrict__ csr_eid,
                                                   const float* __restrict__ z,
                                                   float* __restrict__ out) {
  int gid = blockIdx.x * blockDim.x + threadIdx.x;
  int node = gid >> 6;
  if (node >= N_NODES) return;
  int lane = threadIdx.x & 63;
  int g = lane >> 4, l = lane & 15;
  int rs = rowptr[node];
  int deg = ((node < N_NODES - 1) ? rowptr[node + 1] : E_EDGES) - rs;
  if (deg == 0) return;
  float4 zd = *(const float4*)&z[(size_t)node * HO + l * 4];
  for (int it = g; it < deg; it += 4) {
    int s = csr_src[rs + it];
    int eid = csr_eid[rs + it];
    float4 zs = *(const float4*)&z[(size_t)s * HO + l * 4];
    float v = zs.x * zd.x + zs.y * zd.y + zs.z * zd.z + zs.w * zd.w;
#pragma unroll
    for (int off = 8; off >= 1; off >>= 1) v += __shfl_xor(v, off, 64);
    if (l == 0) out[eid] = v;
  }
}

extern "C" void kernel_launch(void* const* d_in, const int* in_sizes, int n_in,
                              void* d_out, int out_size, void* d_ws, size_t ws_size,
                              hipStream_t stream) {
  const float* x      = (const float*)d_in[0];
  const int*   ei     = (const int*)d_in[1];
  const float* W1     = (const float*)d_in[2];
  const float* a_src1 = (const float*)d_in[3];
  const float* a_dst1 = (const float*)d_in[4];
  const float* b1     = (const float*)d_in[5];
  const float* W2     = (const float*)d_in[6];
  const float* a_src2 = (const float*)d_in[7];
  const float* a_dst2 = (const float*)d_in[8];
  const float* b2     = (const float*)d_in[9];
  const int* src = ei;
  const int* dst = ei + E_EDGES;
  float* logits = (float*)d_out;

  float* zlat = (float*)d_ws;                          // N*64 fp32
  float* als1 = zlat + (size_t)N_NODES * HO;
  float* ald1 = als1 + N_NODES * HEADS;
  float* als2 = ald1 + N_NODES * HEADS;
  float* ald2 = als2 + N_NODES * HEADS;
  int* deg      = (int*)(ald2 + N_NODES * HEADS);
  int* rowptr   = deg + N_NODES;
  int* cursor   = rowptr + N_NODES;
  int* blockSums= cursor + N_NODES;
  int* csr_src  = blockSums + 256;
  int* csr_eid  = csr_src + E_EDGES;
  ushort* hbf   = (ushort*)(csr_eid + E_EDGES);        // N*256 bf16 (h1, then h2)
  ushort* x2bf  = hbf + (size_t)N_NODES * DIM;         // N*256 bf16 (elu(gat1))
  ushort* bt1   = x2bf + (size_t)N_NODES * DIM;        // 2 x 256*256 (W^T bf16)
  ushort* bt2   = bt1 + DIM * DIM;

  dim3 blk(256);
  dim3 gemmGrid((N_NODES + GBM - 1) / GBM, DIM / GBM); // 391 x 2
  int nodeBlocks = (N_NODES * 64 + 255) / 256;
  int edgeThreadBlocks = (E_EDGES + 255) / 256;

  // ---- CSR build (graph shared by both layers) ----
  hipMemsetAsync(deg, 0, N_NODES * sizeof(int), stream);
  hipLaunchKernelGGL(histo, dim3(edgeThreadBlocks), blk, 0, stream, dst, deg);
  hipLaunchKernelGGL(scan1, dim3(SCAN_NBLK), blk, 0, stream, deg, rowptr, blockSums);
  hipLaunchKernelGGL(scan2, dim3(1), blk, 0, stream, blockSums);
  hipLaunchKernelGGL(scan3, dim3(SCAN_NBLK), blk, 0, stream, rowptr, blockSums, cursor);
  hipLaunchKernelGGL(scatter, dim3(edgeThreadBlocks), blk, 0, stream, src, dst, cursor, csr_src, csr_eid);

  // ---- weight conversion (both layers, one launch) ----
  hipLaunchKernelGGL(cvt_T2, dim3(2 * DIM * DIM / 256), blk, 0, stream, W1, W2, bt1, bt2);

  // ---- layer 1 (A = fp32 x, converted in staging) ----
  gemm_mfma<true><<<gemmGrid, blk, 0, stream>>>((const void*)x, bt1, hbf, N_NODES);
  hipLaunchKernelGGL(attn_logits, dim3(nodeBlocks), blk, 0, stream, hbf, a_src1, a_dst1, als1, ald1);
  hipLaunchKernelGGL(agg1, dim3(nodeBlocks), blk, 0, stream, rowptr, csr_src, hbf, als1, ald1, b1, x2bf);

  // ---- layer 2 (A = bf16 x2) ----
  gemm_mfma<false><<<gemmGrid, blk, 0, stream>>>((const void*)x2bf, bt2, hbf, N_NODES);
  hipLaunchKernelGGL(attn_logits, dim3(nodeBlocks), blk, 0, stream, hbf, a_src2, a_dst2, als2, ald2);
  hipLaunchKernelGGL(agg2, dim3(nodeBlocks), blk, 0, stream, rowptr, csr_src, hbf, als2, ald2, b2, zlat);

  // ---- decoder (CSR order: z[dst] register-resident per node) ----
  hipLaunchKernelGGL(decoder_csr, dim3(nodeBlocks), blk, 0, stream, rowptr, csr_src, csr_eid, zlat, logits);
}

// Round 11
// 366.700 us; speedup vs baseline: 1.0758x; 1.0427x over previous
//
#include <hip/hip_runtime.h>
#include <math.h>

#define N_NODES 50000
#define E_EDGES 800000
#define DIM 256      // IN_DIM = HID = 256 (= H*O for both layers)
#define HEADS 4
#define HO 64        // per-head output width (O1 = LAT = 64)
#define NEG_SLOPE 0.2f
#define SCAN_NBLK ((N_NODES + 255) / 256)   // 196

typedef __attribute__((ext_vector_type(8))) short bf16x8;
typedef __attribute__((ext_vector_type(4))) float f32x4;
typedef __attribute__((ext_vector_type(2))) float f32x2;

static __device__ inline ushort f2bf(float f) {
  union { float f; unsigned u; } v; v.f = f;
  unsigned r = (v.u + 0x7fff + ((v.u >> 16) & 1)) >> 16;  // RTNE
  return (ushort)r;
}
static __device__ inline float bf2f(ushort h) {
  union { unsigned u; float f; } v; v.u = ((unsigned)h) << 16;
  return v.f;
}

// Both W (256x256) fp32 -> W^T as bf16 (single plane), one launch
__global__ __launch_bounds__(256) void cvt_T2(const float* __restrict__ W1,
                                              const float* __restrict__ W2,
                                              ushort* __restrict__ bt1,
                                              ushort* __restrict__ bt2) {
  int gidx = blockIdx.x * 256 + threadIdx.x;   // 131072 threads
  const float* W = (gidx < DIM * DIM) ? W1 : W2;
  ushort* bt = (gidx < DIM * DIM) ? bt1 : bt2;
  int idx = gidx & (DIM * DIM - 1);
  int k = idx >> 8, n = idx & 255;
  bt[n * 256 + k] = f2bf(W[idx]);              // W[k][n] -> BT[n][k]
}

// ---------------- bf16 MFMA GEMM: Cbf16(Mx256) = A @ BT^T ----------------
// A fp32 (converted during staging) or bf16 (direct). BT pre-transposed bf16.
// 128x128 tile, 4 waves, 16x16x32 MFMA, single-barrier double-buffered LDS:
// loads for tile t+1 issue before computing tile t; staged regs written to the
// other buffer after MFMA (its readers were fenced by the previous barrier).
#define GBM 128
#define GBK 32
#define LDK 40   // padded LDS k-stride (ushorts): 80B rows, 2-way banks max
#define NKT (DIM / GBK)   // 8 k-steps

template <bool AF32>
__global__ __launch_bounds__(256) void gemm_mfma(const void* __restrict__ Av,
                                                 const ushort* __restrict__ Bt,
                                                 ushort* __restrict__ Cbf, int M) {
  __shared__ __align__(16) ushort As[2][GBM][LDK];
  __shared__ __align__(16) ushort Bs[2][GBM][LDK];
  const int tid = threadIdx.x;
  const int lane = tid & 63;
  const int wave = tid >> 6;
  const int row0 = blockIdx.x * GBM;
  const int col0 = blockIdx.y * GBM;
  const int wm = (wave & 1) * 64;
  const int wn = (wave >> 1) * 64;
  const int rA = lane & 15;
  const int kb = (lane >> 4) * 8;

  f32x4 acc[4][4] = {};
  ushort4 a4[4];   // staged A (fp32 path: 4 chunks of 4)
  bf16x8 a8[2];    // staged A (bf16 path: 2 chunks of 8)
  bf16x8 b8[2];    // staged B

  auto loadA = [&](int k0) {
    if constexpr (AF32) {
      const float* A = (const float*)Av;
#pragma unroll
      for (int qq = 0; qq < 4; ++qq) {
        int q = tid + qq * 256;
        int r = q >> 3, c = q & 7;
        int grow = row0 + r;
        float4 v = make_float4(0.f, 0.f, 0.f, 0.f);
        if (grow < M) v = *(const float4*)&A[(size_t)grow * DIM + k0 + c * 4];
        ushort4 h;
        h.x = f2bf(v.x); h.y = f2bf(v.y); h.z = f2bf(v.z); h.w = f2bf(v.w);
        a4[qq] = h;
      }
    } else {
      const ushort* A = (const ushort*)Av;
#pragma unroll
      for (int qq = 0; qq < 2; ++qq) {
        int q = tid + qq * 256;
        int r = q >> 2, c = q & 3;
        int grow = row0 + r;
        bf16x8 v = {};
        if (grow < M) v = *(const bf16x8*)&A[(size_t)grow * DIM + k0 + c * 8];
        a8[qq] = v;
      }
    }
  };
  auto loadB = [&](int k0) {
#pragma unroll
    for (int qq = 0; qq < 2; ++qq) {
      int q = tid + qq * 256;
      int r = q >> 2, c = q & 3;
      b8[qq] = *(const bf16x8*)&Bt[(size_t)(col0 + r) * DIM + k0 + c * 8];
    }
  };
  auto writeLDS = [&](int buf) {
    if constexpr (AF32) {
#pragma unroll
      for (int qq = 0; qq < 4; ++qq) {
        int q = tid + qq * 256;
        int r = q >> 3, c = q & 7;
        *(ushort4*)&As[buf][r][c * 4] = a4[qq];
      }
    } else {
#pragma unroll
      for (int qq = 0; qq < 2; ++qq) {
        int q = tid + qq * 256;
        int r = q >> 2, c = q & 3;
        *(bf16x8*)&As[buf][r][c * 8] = a8[qq];
      }
    }
#pragma unroll
    for (int qq = 0; qq < 2; ++qq) {
      int q = tid + qq * 256;
      int r = q >> 2, c = q & 3;
      *(bf16x8*)&Bs[buf][r][c * 8] = b8[qq];
    }
  };

  // prologue: stage tile 0
  loadA(0); loadB(0); writeLDS(0);
  __syncthreads();

  int cur = 0;
  for (int t = 0; t < NKT; ++t) {
    // issue next-tile global loads first (latency hides under MFMA below)
    if (t + 1 < NKT) { loadA((t + 1) * GBK); loadB((t + 1) * GBK); }

    bf16x8 af[4], bfr[4];
#pragma unroll
    for (int mi = 0; mi < 4; ++mi) af[mi] = *(const bf16x8*)&As[cur][wm + mi * 16 + rA][kb];
#pragma unroll
    for (int ni = 0; ni < 4; ++ni) bfr[ni] = *(const bf16x8*)&Bs[cur][wn + ni * 16 + rA][kb];
#pragma unroll
    for (int mi = 0; mi < 4; ++mi)
#pragma unroll
      for (int ni = 0; ni < 4; ++ni)
        acc[mi][ni] = __builtin_amdgcn_mfma_f32_16x16x32_bf16(af[mi], bfr[ni], acc[mi][ni], 0, 0, 0);

    if (t + 1 < NKT) writeLDS(cur ^ 1);
    __syncthreads();
    cur ^= 1;
  }

  // C/D layout: col = lane&15, row = (lane>>4)*4 + reg. Emit bf16.
#pragma unroll
  for (int mi = 0; mi < 4; ++mi) {
    int rbase = row0 + wm + mi * 16 + (lane >> 4) * 4;
#pragma unroll
    for (int ni = 0; ni < 4; ++ni) {
      int col = col0 + wn + ni * 16 + (lane & 15);
#pragma unroll
      for (int r = 0; r < 4; ++r) {
        int row = rbase + r;
        if (row < M) Cbf[(size_t)row * DIM + col] = f2bf(acc[mi][ni][r]);
      }
    }
  }
}

// ---------------- per-node attention logits (bf16 h) ----------------
__global__ __launch_bounds__(256) void attn_logits(const ushort* __restrict__ h,
                                                   const float* __restrict__ a_src,
                                                   const float* __restrict__ a_dst,
                                                   float* __restrict__ al_s,
                                                   float* __restrict__ al_d) {
  int gid = blockIdx.x * blockDim.x + threadIdx.x;
  int node = gid >> 6;
  int lane = threadIdx.x & 63;
  if (node >= N_NODES) return;
  ushort4 hv = *(const ushort4*)&h[(size_t)node * DIM + lane * 4];
  float4 as = *(const float4*)&a_src[lane * 4];
  float4 ad = *(const float4*)&a_dst[lane * 4];
  float h0 = bf2f(hv.x), h1 = bf2f(hv.y), h2 = bf2f(hv.z), h3 = bf2f(hv.w);
  float s = h0 * as.x + h1 * as.y + h2 * as.z + h3 * as.w;
  float d = h0 * ad.x + h1 * ad.y + h2 * ad.z + h3 * ad.w;
#pragma unroll
  for (int off = 8; off >= 1; off >>= 1) {
    s += __shfl_xor(s, off, 64);
    d += __shfl_xor(d, off, 64);
  }
  if ((lane & 15) == 0) {
    int head = lane >> 4;
    al_s[node * HEADS + head] = s;
    al_d[node * HEADS + head] = d;
  }
}

// ---------------- CSR build ----------------
__global__ __launch_bounds__(256) void histo(const int* __restrict__ dst, int* __restrict__ deg) {
  int e = blockIdx.x * blockDim.x + threadIdx.x;
  if (e < E_EDGES) atomicAdd(&deg[dst[e]], 1);
}

__global__ __launch_bounds__(256) void scan1(const int* __restrict__ deg,
                                             int* __restrict__ excl,
                                             int* __restrict__ blockSums) {
  __shared__ int tmp[256];
  int i = blockIdx.x * 256 + threadIdx.x;
  int v = (i < N_NODES) ? deg[i] : 0;
  tmp[threadIdx.x] = v;
  __syncthreads();
  for (int off = 1; off < 256; off <<= 1) {
    int t = (threadIdx.x >= off) ? tmp[threadIdx.x - off] : 0;
    __syncthreads();
    tmp[threadIdx.x] += t;
    __syncthreads();
  }
  int incl = tmp[threadIdx.x];
  if (i < N_NODES) excl[i] = incl - v;
  if (threadIdx.x == 255) blockSums[blockIdx.x] = incl;
}

__global__ __launch_bounds__(256) void scan2(int* __restrict__ blockSums) {
  __shared__ int tmp[256];
  int i = threadIdx.x;
  int v = (i < SCAN_NBLK) ? blockSums[i] : 0;
  tmp[i] = v;
  __syncthreads();
  for (int off = 1; off < 256; off <<= 1) {
    int t = (i >= off) ? tmp[i - off] : 0;
    __syncthreads();
    tmp[i] += t;
    __syncthreads();
  }
  if (i < SCAN_NBLK) blockSums[i] = tmp[i] - v;  // exclusive
}

__global__ __launch_bounds__(256) void scan3(int* __restrict__ excl,
                                             const int* __restrict__ blockSums,
                                             int* __restrict__ cursor) {
  int i = blockIdx.x * 256 + threadIdx.x;
  if (i < N_NODES) {
    int r = excl[i] + blockSums[blockIdx.x];
    excl[i] = r;
    cursor[i] = r;
  }
}

__global__ __launch_bounds__(256) void scatter(const int* __restrict__ src,
                                               const int* __restrict__ dst,
                                               int* __restrict__ cursor,
                                               int* __restrict__ csr_src) {
  int e = blockIdx.x * blockDim.x + threadIdx.x;
  if (e >= E_EDGES) return;
  int pos = atomicAdd(&cursor[dst[e]], 1);
  csr_src[pos] = src[e];
}

// ---------------- aggregation core: half-wave per edge, bf16 h rows (R4 layout) ----------------
// lane: li = lane&31, half = lane>>5; lane covers 8 cols c0 = li*8; head = li>>3.
// virtual edge index it == deg is the self-loop. Packed f32x2 accumulate (v_pk_fma_f32).
#define AGG_BODY(S)                                                         \
  {                                                                         \
    float e0 = als[(S) * HEADS + head] + aldv;                              \
    e0 = e0 > 0.f ? e0 : NEG_SLOPE * e0;                                    \
    float p = __expf(e0);                                                   \
    bf16x8 hv = *(const bf16x8*)&hbf[(size_t)(S) * DIM + c0];               \
    den += p;                                                               \
    const uint* uu = (const uint*)&hv;                                      \
    f32x2 pp = {p, p};                                                      \
    _Pragma("unroll")                                                       \
    for (int q = 0; q < 4; ++q) {                                           \
      f32x2 hh;                                                             \
      hh.x = __uint_as_float(uu[q] << 16);                                  \
      hh.y = __uint_as_float(uu[q] & 0xffff0000u);                          \
      acc2[q] += pp * hh;                                                   \
    }                                                                       \
  }

// shared gather loop: 3 edges in flight per half-wave
#define AGG_LOOP                                                            \
  int rs = rowptr[node];                                                    \
  int deg = ((node < N_NODES - 1) ? rowptr[node + 1] : E_EDGES) - rs;       \
  float aldv = ald[node * HEADS + head];                                    \
  float den = 0.f;                                                          \
  f32x2 acc2[4] = {};                                                       \
  int total = deg + 1;                                                      \
  int it = half;                                                            \
  for (; it + 4 < total; it += 6) {                                         \
    int s0 = csr_src[rs + it];                                              \
    int s1 = csr_src[rs + it + 2];                                          \
    int s2 = (it + 4 < deg) ? csr_src[rs + it + 4] : node;                  \
    AGG_BODY(s0)                                                            \
    AGG_BODY(s1)                                                            \
    AGG_BODY(s2)                                                            \
  }                                                                         \
  for (; it < total; it += 2) {                                             \
    int s0 = (it < deg) ? csr_src[rs + it] : node;                          \
    AGG_BODY(s0)                                                            \
  }                                                                         \
  den += __shfl_xor(den, 32, 64);                                           \
  float accs[8];                                                            \
  _Pragma("unroll")                                                         \
  for (int q = 0; q < 4; ++q) {                                             \
    accs[2 * q] = acc2[q].x + __shfl_xor(acc2[q].x, 32, 64);                \
    accs[2 * q + 1] = acc2[q].y + __shfl_xor(acc2[q].y, 32, 64);            \
  }

// layer-1: finalize = +bias, ELU -> bf16 x2 (layer-2 GEMM A-operand)
__global__ __launch_bounds__(256) void agg1(const int* __restrict__ rowptr,
                                            const int* __restrict__ csr_src,
                                            const ushort* __restrict__ hbf,
                                            const float* __restrict__ als,
                                            const float* __restrict__ ald,
                                            const float* __restrict__ bias,
                                            ushort* __restrict__ x2) {
  int gid = blockIdx.x * blockDim.x + threadIdx.x;
  int node = gid >> 6;
  if (node >= N_NODES) return;
  int lane = threadIdx.x & 63;
  int li = lane & 31, half = lane >> 5;
  int head = li >> 3;
  int c0 = li * 8;
  AGG_LOOP
  if (half == 0) {
    float inv = 1.f / den;
    ushort4 o0, o1;
    float r[8];
#pragma unroll
    for (int j = 0; j < 8; ++j) {
      r[j] = accs[j] * inv + bias[c0 + j];
      r[j] = r[j] > 0.f ? r[j] : expm1f(r[j]);   // ELU
    }
    o0.x = f2bf(r[0]); o0.y = f2bf(r[1]); o0.z = f2bf(r[2]); o0.w = f2bf(r[3]);
    o1.x = f2bf(r[4]); o1.y = f2bf(r[5]); o1.z = f2bf(r[6]); o1.w = f2bf(r[7]);
    *(ushort4*)&x2[(size_t)node * DIM + c0] = o0;
    *(ushort4*)&x2[(size_t)node * DIM + c0 + 4] = o1;
  }
}

// layer-2: finalize = mean over heads, +b2 -> fp32 z (N x 64)
__global__ __launch_bounds__(256) void agg2(const int* __restrict__ rowptr,
                                            const int* __restrict__ csr_src,
                                            const ushort* __restrict__ hbf,
                                            const float* __restrict__ als,
                                            const float* __restrict__ ald,
                                            const float* __restrict__ b2,
                                            float* __restrict__ z) {
  int gid = blockIdx.x * blockDim.x + threadIdx.x;
  int node = gid >> 6;
  if (node >= N_NODES) return;
  int lane = threadIdx.x & 63;
  int li = lane & 31, half = lane >> 5;
  int head = li >> 3;
  int c0 = li * 8;
  AGG_LOOP
  float inv = 1.f / den;
  float r[8];
#pragma unroll
  for (int j = 0; j < 8; ++j) {
    r[j] = accs[j] * inv;
    r[j] += __shfl_xor(r[j], 8, 64);    // head 0<->1 (and 2<->3)
    r[j] += __shfl_xor(r[j], 16, 64);   // heads (0,1)<->(2,3)
  }
  if (lane < 8) {   // half==0, li<8: cols li*8..li*8+7 of the 64-wide z row
    int zc = li * 8;
    float4 v0 = make_float4(r[0] * 0.25f + b2[zc + 0], r[1] * 0.25f + b2[zc + 1],
                            r[2] * 0.25f + b2[zc + 2], r[3] * 0.25f + b2[zc + 3]);
    float4 v1 = make_float4(r[4] * 0.25f + b2[zc + 4], r[5] * 0.25f + b2[zc + 5],
                            r[6] * 0.25f + b2[zc + 6], r[7] * 0.25f + b2[zc + 7]);
    *(float4*)&z[(size_t)node * HO + zc] = v0;
    *(float4*)&z[(size_t)node * HO + zc + 4] = v1;
  }
}

// ---------------- decoder ----------------
__global__ __launch_bounds__(256) void decoder(const int* __restrict__ src,
                                               const int* __restrict__ dst,
                                               const float* __restrict__ z,
                                               float* __restrict__ out) {
  long long gid = (long long)blockIdx.x * blockDim.x + threadIdx.x;
  int e = (int)(gid >> 4);
  if (e >= E_EDGES) return;
  int l = threadIdx.x & 15;
  int s = src[e];
  int d = dst[e];
  float4 a = *(const float4*)&z[(size_t)s * HO + l * 4];
  float4 b = *(const float4*)&z[(size_t)d * HO + l * 4];
  float v = a.x * b.x + a.y * b.y + a.z * b.z + a.w * b.w;
#pragma unroll
  for (int off = 8; off >= 1; off >>= 1) v += __shfl_xor(v, off, 64);
  if (l == 0) out[e] = v;
}

extern "C" void kernel_launch(void* const* d_in, const int* in_sizes, int n_in,
                              void* d_out, int out_size, void* d_ws, size_t ws_size,
                              hipStream_t stream) {
  const float* x      = (const float*)d_in[0];
  const int*   ei     = (const int*)d_in[1];
  const float* W1     = (const float*)d_in[2];
  const float* a_src1 = (const float*)d_in[3];
  const float* a_dst1 = (const float*)d_in[4];
  const float* b1     = (const float*)d_in[5];
  const float* W2     = (const float*)d_in[6];
  const float* a_src2 = (const float*)d_in[7];
  const float* a_dst2 = (const float*)d_in[8];
  const float* b2     = (const float*)d_in[9];
  const int* src = ei;
  const int* dst = ei + E_EDGES;
  float* logits = (float*)d_out;

  float* zlat = (float*)d_ws;                          // N*64 fp32
  float* als1 = zlat + (size_t)N_NODES * HO;
  float* ald1 = als1 + N_NODES * HEADS;
  float* als2 = ald1 + N_NODES * HEADS;
  float* ald2 = als2 + N_NODES * HEADS;
  int* deg      = (int*)(ald2 + N_NODES * HEADS);
  int* rowptr   = deg + N_NODES;
  int* cursor   = rowptr + N_NODES;
  int* blockSums= cursor + N_NODES;
  int* csr_src  = blockSums + 256;
  ushort* hbf   = (ushort*)(csr_src + E_EDGES);        // N*256 bf16 (h1, then h2)
  ushort* x2bf  = hbf + (size_t)N_NODES * DIM;         // N*256 bf16 (elu(gat1))
  ushort* bt1   = x2bf + (size_t)N_NODES * DIM;        // 2 x 256*256 (W^T bf16)
  ushort* bt2   = bt1 + DIM * DIM;

  dim3 blk(256);
  dim3 gemmGrid((N_NODES + GBM - 1) / GBM, DIM / GBM); // 391 x 2
  int nodeBlocks = (N_NODES * 64 + 255) / 256;
  int edgeThreadBlocks = (E_EDGES + 255) / 256;
  int decBlocks  = (int)(((long long)E_EDGES * 16 + 255) / 256);

  // ---- CSR build (graph shared by both layers) ----
  hipMemsetAsync(deg, 0, N_NODES * sizeof(int), stream);
  hipLaunchKernelGGL(histo, dim3(edgeThreadBlocks), blk, 0, stream, dst, deg);
  hipLaunchKernelGGL(scan1, dim3(SCAN_NBLK), blk, 0, stream, deg, rowptr, blockSums);
  hipLaunchKernelGGL(scan2, dim3(1), blk, 0, stream, blockSums);
  hipLaunchKernelGGL(scan3, dim3(SCAN_NBLK), blk, 0, stream, rowptr, blockSums, cursor);
  hipLaunchKernelGGL(scatter, dim3(edgeThreadBlocks), blk, 0, stream, src, dst, cursor, csr_src);

  // ---- weight conversion (both layers, one launch) ----
  hipLaunchKernelGGL(cvt_T2, dim3(2 * DIM * DIM / 256), blk, 0, stream, W1, W2, bt1, bt2);

  // ---- layer 1 (A = fp32 x, converted in staging) ----
  gemm_mfma<true><<<gemmGrid, blk, 0, stream>>>((const void*)x, bt1, hbf, N_NODES);
  hipLaunchKernelGGL(attn_logits, dim3(nodeBlocks), blk, 0, stream, hbf, a_src1, a_dst1, als1, ald1);
  hipLaunchKernelGGL(agg1, dim3(nodeBlocks), blk, 0, stream, rowptr, csr_src, hbf, als1, ald1, b1, x2bf);

  // ---- layer 2 (A = bf16 x2) ----
  gemm_mfma<false><<<gemmGrid, blk, 0, stream>>>((const void*)x2bf, bt2, hbf, N_NODES);
  hipLaunchKernelGGL(attn_logits, dim3(nodeBlocks), blk, 0, stream, hbf, a_src2, a_dst2, als2, ald2);
  hipLaunchKernelGGL(agg2, dim3(nodeBlocks), blk, 0, stream, rowptr, csr_src, hbf, als2, ald2, b2, zlat);

  // ---- decoder ----
  hipLaunchKernelGGL(decoder, dim3(decBlocks), blk, 0, stream, src, dst, zlat, logits);
}